// Round 7
// baseline (4377.084 us; speedup 1.0000x reference)
//
#include <hip/hip_runtime.h>

// ---------------- problem constants ----------------
// S=512 seq, B=64 batch, I=256 in, H=1024 hidden, 4H=4096 gates
// Wx = [W1 W3 W5 W7] (input side), Wh = [W2 W4 W6 W8] (hidden side)
// out: h_seq (512,64,1024) fp32, then h_final (64,1024), c_final (64,1024)

// ---------------- workspace layout (bytes) ----------------
#define OFF_XB    0ul          // bf16 x      [512][64][256]   = 16 MiB
#define OFF_WXP   16777216ul   // bf16 Wx^T   [4096][256]      =  2 MiB (packed [col][k])
#define OFF_WHP   18874368ul   // bf16 Wh^T   [4096][1024]     =  8 MiB (packed [col][k], PRE-SWIZZLED)
#define OFF_BIAS  27262976ul   // f32 bx+bh   [4096]
#define OFF_HBUF  27279360ul   // bf16 h      [2][64][1024]    = 256 KiB double buffer
#define OFF_CNR   27541504ul   // int canary  [2][64][4] = 512 ints (per producer WAVE)

typedef __attribute__((ext_vector_type(8))) __bf16 bf16x8;
typedef __attribute__((ext_vector_type(4))) float  floatx4;

struct KPtrs { const float* p[17]; };

__device__ __forceinline__ unsigned short f2bf(float f) {  // fp32 -> bf16 RTN-even
  unsigned int u = __float_as_uint(f);
  u += 0x7fffu + ((u >> 16) & 1u);
  return (unsigned short)(u >> 16);
}

__device__ __forceinline__ bf16x8 ld16(const unsigned short* p) {
  return *(const bf16x8*)p;   // cached global_load_dwordx4
}

// L3-coherent (agent-scope, L2-bypassing) 16B load as 2x relaxed u64 atomics
__device__ __forceinline__ bf16x8 ldsys16(const unsigned short* p) {
  unsigned long long a =
      __hip_atomic_load((const unsigned long long*)p,       __ATOMIC_RELAXED, __HIP_MEMORY_SCOPE_AGENT);
  unsigned long long b =
      __hip_atomic_load((const unsigned long long*)(p + 4), __ATOMIC_RELAXED, __HIP_MEMORY_SCOPE_AGENT);
  unsigned long long arr[2] = {a, b};
  bf16x8 r;
  __builtin_memcpy(&r, arr, 16);
  return r;
}

__device__ __forceinline__ int lduc32(const int* p) {
  return __hip_atomic_load(p, __ATOMIC_RELAXED, __HIP_MEMORY_SCOPE_AGENT);
}

__device__ __forceinline__ float fsig(float x) {
  return __builtin_amdgcn_rcpf(1.f + __expf(-x));
}
__device__ __forceinline__ float ftanh(float x) {
  return 1.f - 2.f * __builtin_amdgcn_rcpf(1.f + __expf(2.f * x));
}

// ---------------- pack/convert + state init ----------------
__global__ void pack_kernel(KPtrs P, unsigned char* ws) {
  unsigned short* xb   = (unsigned short*)(ws + OFF_XB);
  unsigned short* wxp  = (unsigned short*)(ws + OFF_WXP);
  unsigned short* whp  = (unsigned short*)(ws + OFF_WHP);
  float*          bias = (float*)(ws + OFF_BIAS);
  unsigned int*   hb32 = (unsigned int*)(ws + OFF_HBUF);
  int*            cnr  = (int*)(ws + OFF_CNR);
  const float* x = P.p[0];

  const long tid = (long)blockIdx.x * blockDim.x + threadIdx.x;
  const long nth = (long)gridDim.x * blockDim.x;

  for (long e = tid; e < 8388608l; e += nth)       // x -> bf16, same flat layout
    xb[e] = f2bf(x[e]);
  for (long e = tid; e < 1048576l; e += nth) {     // Wx packed [col][k]
    int c = (int)(e >> 8), i = (int)(e & 255);
    int gg = c >> 10, j = c & 1023;
    wxp[e] = f2bf(P.p[1 + 4 * gg][i * 1024 + j]);  // W1,W3,W5,W7
  }
  // Wh packed [col][k], PRE-SWIZZLED: element (c,k) stored at k ^ ((c&7)<<3)
  // so LDS staging is a plain linear copy and ds_read_b128 with the same XOR
  // on the read side is bank-balanced. (Verified correct in R3..R6.)
  for (long e = tid; e < 4194304l; e += nth) {
    int c = (int)(e >> 10), k = (int)(e & 1023);
    int gg = c >> 10, j = c & 1023;
    long dst = ((long)c << 10) | (long)(k ^ ((c & 7) << 3));
    whp[dst] = f2bf(P.p[3 + 4 * gg][k * 1024 + j]);  // W2,W4,W6,W8
  }
  for (long e = tid; e < 4096l; e += nth) {        // bx + bh
    int gg = (int)(e >> 10), j = (int)(e & 1023);
    bias[e] = P.p[2 + 4 * gg][j] + P.p[4 + 4 * gg][j];
  }
  // h double buffer = 0 (UC stores: land at the L3 coherence point)
  for (long e = tid; e < 65536l; e += nth)
    __hip_atomic_store(&hb32[e], 0u, __ATOMIC_RELAXED, __HIP_MEMORY_SCOPE_AGENT);
  // canaries = -1  (h_{-1} ready)
  for (long e = tid; e < 512l; e += nth)
    __hip_atomic_store(&cnr[e], -1, __ATOMIC_RELAXED, __HIP_MEMORY_SCOPE_AGENT);
}

// ---------------- persistent fused LSTM ----------------
// 128 blocks (proven co-resident) = 2 batch-groups (32 batches) x 64
// hidden-slices (16 units x 4 gates), 4 waves K-split.
//
// R6 structure with two fixes:
//  (1) FORCED co-resident h burst: after the 16 ldsys16, an empty volatile
//      asm consumes ALL 16 results at once -> 64 distinct dest VGPRs must be
//      simultaneously live -> no intermediate s_waitcnt, loads issue
//      back-to-back, ONE L3 round trip. (R1/R3/R5/R6 all lost to regalloc
//      chunk-serialization; VGPR_Count >= ~190 is the success signature.)
//  (2) s_sleep(1)-paced detect poll (R6 removed it; 512 waves tight-polling
//      the canary lines congest L3 and slow producers: R4->R6 = +360us).
// Protocol safety identical to R6 (ran correct twice, absmax 0.0044).
__global__ void __launch_bounds__(256, 1)
lstm_kernel(const unsigned char* __restrict__ ws, float* __restrict__ out) {
  const unsigned short* xb   = (const unsigned short*)(ws + OFF_XB);
  const unsigned short* wxp  = (const unsigned short*)(ws + OFF_WXP);
  const unsigned short* whp  = (const unsigned short*)(ws + OFF_WHP);
  const float*          bias = (const float*)(ws + OFF_BIAS);
  unsigned short*       hbuf = (unsigned short*)(ws + OFF_HBUF);
  int*                  cnr  = (int*)(ws + OFF_CNR);

  const int tid = threadIdx.x;
  const int wv = tid >> 6, lane = tid & 63;
  const int r = lane & 15, q = lane >> 4;          // MFMA frag row + k-quad
  const int s = blockIdx.x & 63, g = blockIdx.x >> 6;

  __shared__ unsigned short whl[65536];            // 128 KiB swizzled Wh slice
  __shared__ float pc[4][8][64][4];                // 32 KiB cross-wave reduce
                                                   // total 160 KiB (CU max)

  // ---- stage Wh slice into LDS (linear copy; swizzle pre-baked in whp) ----
  for (int ch = tid; ch < 8192; ch += 256) {
    const int le = ch * 8;                         // bf16 element index in whl
    const int rl = le >> 10, k8 = le & 1023;       // local row 0..63
    const int cg = (rl >> 4) * 1024 + s * 16 + (rl & 15);   // global gate col
    *(bf16x8*)&whl[le] = ld16(whp + (long)cg * 1024 + k8);
  }

  // ---- Wx fragments in registers (loop-invariant, 32 VGPR) ----
  bf16x8 wxf[4][2];
#pragma unroll
  for (int nt = 0; nt < 4; ++nt) {
    const int c = nt * 1024 + s * 16 + r;
#pragma unroll
    for (int kk = 0; kk < 2; ++kk)
      wxf[nt][kk] = ld16(wxp + (long)c * 256 + wv * 64 + kk * 32 + q * 8);
  }

  // epilogue mapping: thread -> (batches eb, eb+16 ; hidden col ej)
  const int ej = tid & 15, eb = tid >> 4;
  const int lidx = ej | ((eb >> 2) << 4), rg = eb & 3;   // C-frag coords
  float bs[4];
#pragma unroll
  for (int gt = 0; gt < 4; ++gt) bs[gt] = bias[gt * 1024 + s * 16 + ej];

  const unsigned short* xa0 = xb + (long)(g * 32 + r) * 256 + q * 8;
  const int rs = (r & 7) << 3;                     // LDS XOR swizzle term
  // consumer wave wv reads k in [wv*256, wv*256+256) -> producers
  // s' in [wv*16, wv*16+16), all 4 publisher waves: one canary per lane.
  const int cidx = g * 256 + (wv * 16 + (lane >> 2)) * 4 + (lane & 3);
  const int pidx = g * 256 + s * 4 + wv;           // my producer canary

  float cst[2] = {0.f, 0.f};
  __syncthreads();                                 // whl staged

  for (int t = 0; t < 512; ++t) {
    // ---- canary load first (oldest in flight; latency hides under x) ----
    int cv = lduc32(&cnr[cidx]);

    // ---- x loads + x-side K (independent of peers) ----
    const unsigned short* xaT = xa0 + (long)t * 16384;
    bf16x8 xv[2][2];
#pragma unroll
    for (int kk = 0; kk < 2; ++kk) {
      xv[0][kk] = ld16(xaT + wv * 64 + kk * 32);
      xv[1][kk] = ld16(xaT + 16 * 256 + wv * 64 + kk * 32);
    }

    floatx4 acc[2][4];
#pragma unroll
    for (int mt = 0; mt < 2; ++mt)
#pragma unroll
      for (int nt = 0; nt < 4; ++nt) acc[mt][nt] = (floatx4){0.f, 0.f, 0.f, 0.f};

#pragma unroll
    for (int kk = 0; kk < 2; ++kk)
#pragma unroll
      for (int nt = 0; nt < 4; ++nt) {
        acc[0][nt] = __builtin_amdgcn_mfma_f32_16x16x32_bf16(xv[0][kk], wxf[nt][kk], acc[0][nt], 0, 0, 0);
        acc[1][nt] = __builtin_amdgcn_mfma_f32_16x16x32_bf16(xv[1][kk], wxf[nt][kk], acc[1][nt], 0, 0, 0);
      }

    // ---- detection: paced poll on this wave's 64 producer-wave canaries ----
    const int need = t - 1;
    if (!__all(cv >= need)) {
      do {
        __builtin_amdgcn_s_sleep(1);   // pace: unpaced polls congest L3 (R6)
        cv = lduc32(&cnr[cidx]);
      } while (!__all(cv >= need));
    }
    asm volatile("" ::: "memory");   // no h load may hoist above the gate

    // ---- h burst: 32 u64/thread; empty-asm consume forces all 16 results
    //      live at once -> back-to-back issue, single L3 round trip ----
    const unsigned short* ha =
        hbuf + (long)((t - 1) & 1) * 65536 + ((long)g * 32 + r) * 1024 + q * 8;
    bf16x8 hv0[8], hv1[8];
#pragma unroll
    for (int kk = 0; kk < 8; ++kk) {
      const int k0 = wv * 256 + kk * 32;
      hv0[kk] = ldsys16(ha + k0);
      hv1[kk] = ldsys16(ha + 16 * 1024 + k0);
    }
    asm volatile("" ::
        "v"(hv0[0]), "v"(hv0[1]), "v"(hv0[2]), "v"(hv0[3]),
        "v"(hv0[4]), "v"(hv0[5]), "v"(hv0[6]), "v"(hv0[7]),
        "v"(hv1[0]), "v"(hv1[1]), "v"(hv1[2]), "v"(hv1[3]),
        "v"(hv1[4]), "v"(hv1[5]), "v"(hv1[6]), "v"(hv1[7]));
    __builtin_amdgcn_sched_barrier(0);   // MFMAs stay below the burst

    // ---- h-side K from LDS weights ----
#pragma unroll
    for (int kk = 0; kk < 8; ++kk) {
      bf16x8 wb[4];
      const int el = wv * 256 + ((kk * 32 + q * 8) ^ rs);
#pragma unroll
      for (int nt = 0; nt < 4; ++nt)
        wb[nt] = *(const bf16x8*)&whl[(nt * 16 + r) * 1024 + el];
#pragma unroll
      for (int nt = 0; nt < 4; ++nt) {
        acc[0][nt] = __builtin_amdgcn_mfma_f32_16x16x32_bf16(hv0[kk], wb[nt], acc[0][nt], 0, 0, 0);
        acc[1][nt] = __builtin_amdgcn_mfma_f32_16x16x32_bf16(hv1[kk], wb[nt], acc[1][nt], 0, 0, 0);
      }
    }

    // ---- cross-wave K reduction (sync1: nothing young in flight, cheap) ----
#pragma unroll
    for (int mt = 0; mt < 2; ++mt)
#pragma unroll
      for (int nt = 0; nt < 4; ++nt)
        *(floatx4*)(&pc[wv][mt * 4 + nt][lane][0]) = acc[mt][nt];
    __syncthreads();

    // ---- gates + state update ----
    float hvv[2];
#pragma unroll
    for (int e = 0; e < 2; ++e) {
      float gs[4];
#pragma unroll
      for (int gt = 0; gt < 4; ++gt)
        gs[gt] = bs[gt] + pc[0][e * 4 + gt][lidx][rg] + pc[1][e * 4 + gt][lidx][rg] +
                 pc[2][e * 4 + gt][lidx][rg] + pc[3][e * 4 + gt][lidx][rg];
      const float f = fsig(gs[0]), ii = fsig(gs[1]), o = fsig(gs[2]);
      const float cd = ftanh(gs[3]);
      cst[e] = f * cst[e] + ii * cd;
      hvv[e] = o * ftanh(cst[e]);
    }

    // sync2: pc reads complete before next step's pc writes; nothing issued
    // since sync1 -> drains nothing.
    __syncthreads();

    // ---- publish h_t (UC stores), per-wave ack, per-wave canary ----
#pragma unroll
    for (int e = 0; e < 2; ++e) {
      unsigned short hb16 = f2bf(hvv[e]);
      unsigned short nbv = (unsigned short)__shfl_xor((int)hb16, 1, 64);
      if ((ej & 1) == 0) {
        unsigned int pv = (unsigned int)hb16 | ((unsigned int)nbv << 16);
        unsigned int* hp = (unsigned int*)(hbuf + (long)(t & 1) * 65536 +
            (long)(g * 32 + e * 16 + eb) * 1024 + s * 16 + ej);
        __hip_atomic_store(hp, pv, __ATOMIC_RELAXED, __HIP_MEMORY_SCOPE_AGENT);
      }
    }
    // per-wave: wait ONLY this wave's stores acked at L3, then canary.
    asm volatile("s_waitcnt vmcnt(0)" ::: "memory");
    if (lane == 0)
      __hip_atomic_store(&cnr[pidx], t, __ATOMIC_RELAXED, __HIP_MEMORY_SCOPE_AGENT);

    // ---- h_seq / finals: cached stores, issued AFTER the canary so they
    // never sit in front of the publish ack ----
#pragma unroll
    for (int e = 0; e < 2; ++e) {
      const long ob = (long)(g * 32 + e * 16 + eb) * 1024 + s * 16 + ej;
      out[(long)t * 65536 + ob] = hvv[e];
      if (t == 511) {
        out[33554432l + ob] = hvv[e];
        out[33619968l + ob] = cst[e];
      }
    }
  }
}

extern "C" void kernel_launch(void* const* d_in, const int* in_sizes, int n_in,
                              void* d_out, int out_size, void* d_ws, size_t ws_size,
                              hipStream_t stream) {
  (void)in_sizes; (void)n_in; (void)out_size; (void)ws_size;
  KPtrs P;
  for (int i = 0; i < 17; ++i) P.p[i] = (const float*)d_in[i];
  pack_kernel<<<dim3(2048), dim3(256), 0, stream>>>(P, (unsigned char*)d_ws);
  lstm_kernel<<<dim3(128), dim3(256), 0, stream>>>((const unsigned char*)d_ws, (float*)d_out);
}

// Round 8
// 3068.099 us; speedup vs baseline: 1.4266x; 1.4266x over previous
//
#include <hip/hip_runtime.h>

// ---------------- problem constants ----------------
// S=512 seq, B=64 batch, I=256 in, H=1024 hidden, 4H=4096 gates
// Wx = [W1 W3 W5 W7] (input side), Wh = [W2 W4 W6 W8] (hidden side)
// out: h_seq (512,64,1024) fp32, then h_final (64,1024), c_final (64,1024)

// ---------------- workspace layout (bytes) ----------------
#define OFF_XB    0ul          // bf16 x      [512][64][256]   = 16 MiB
#define OFF_WXP   16777216ul   // bf16 Wx^T   [4096][256]      =  2 MiB (packed [col][k])
#define OFF_WHP   18874368ul   // bf16 Wh^T   [4096][1024]     =  8 MiB (packed [col][k])
#define OFF_BIAS  27262976ul   // f32 bx+bh   [4096]
#define OFF_HBUF  27279360ul   // bf16 h      [2][64][1024]    = 256 KiB double buffer
#define OFF_FLG   27541504ul   // int flags   [128]  (plain UC stores, no RMW)

typedef __attribute__((ext_vector_type(8))) __bf16 bf16x8;
typedef __attribute__((ext_vector_type(4))) float  floatx4;

struct KPtrs { const float* p[17]; };

__device__ __forceinline__ unsigned short f2bf(float f) {  // fp32 -> bf16 RTN-even
  unsigned int u = __float_as_uint(f);
  u += 0x7fffu + ((u >> 16) & 1u);
  return (unsigned short)(u >> 16);
}

__device__ __forceinline__ bf16x8 ld16(const unsigned short* p) {
  return *(const bf16x8*)p;   // cached global_load_dwordx4
}

// L3-coherent (UC, L2-bypassing) 16B load as 2x relaxed u64 atomic loads
__device__ __forceinline__ bf16x8 ldsys16(const unsigned short* p) {
  unsigned long long a =
      __hip_atomic_load((const unsigned long long*)p,       __ATOMIC_RELAXED, __HIP_MEMORY_SCOPE_AGENT);
  unsigned long long b =
      __hip_atomic_load((const unsigned long long*)(p + 4), __ATOMIC_RELAXED, __HIP_MEMORY_SCOPE_AGENT);
  unsigned long long arr[2] = {a, b};
  bf16x8 r;
  __builtin_memcpy(&r, arr, 16);
  return r;
}

__device__ __forceinline__ float fsig(float x) {
  return __builtin_amdgcn_rcpf(1.f + __expf(-x));
}
__device__ __forceinline__ float ftanh(float x) {
  return 1.f - 2.f * __builtin_amdgcn_rcpf(1.f + __expf(2.f * x));
}

// ---------------- pack/convert + state init ----------------
__global__ void pack_kernel(KPtrs P, unsigned char* ws) {
  unsigned short* xb   = (unsigned short*)(ws + OFF_XB);
  unsigned short* wxp  = (unsigned short*)(ws + OFF_WXP);
  unsigned short* whp  = (unsigned short*)(ws + OFF_WHP);
  float*          bias = (float*)(ws + OFF_BIAS);
  unsigned int*   hb32 = (unsigned int*)(ws + OFF_HBUF);
  int*            flg  = (int*)(ws + OFF_FLG);
  const float* x = P.p[0];

  const long tid = (long)blockIdx.x * blockDim.x + threadIdx.x;
  const long nth = (long)gridDim.x * blockDim.x;

  for (long e = tid; e < 8388608l; e += nth)       // x -> bf16, same flat layout
    xb[e] = f2bf(x[e]);
  for (long e = tid; e < 1048576l; e += nth) {     // Wx packed [col][k]
    int c = (int)(e >> 8), i = (int)(e & 255);
    int gg = c >> 10, j = c & 1023;
    wxp[e] = f2bf(P.p[1 + 4 * gg][i * 1024 + j]);  // W1,W3,W5,W7
  }
  for (long e = tid; e < 4194304l; e += nth) {     // Wh packed [col][k]
    int c = (int)(e >> 10), k = (int)(e & 1023);
    int gg = c >> 10, j = c & 1023;
    whp[e] = f2bf(P.p[3 + 4 * gg][k * 1024 + j]);  // W2,W4,W6,W8
  }
  for (long e = tid; e < 4096l; e += nth) {        // bx + bh
    int gg = (int)(e >> 10), j = (int)(e & 1023);
    bias[e] = P.p[2 + 4 * gg][j] + P.p[4 + 4 * gg][j];
  }
  // h double buffer = 0 (UC stores: land at the L3 coherence point)
  for (long e = tid; e < 65536l; e += nth)
    __hip_atomic_store(&hb32[e], 0u, __ATOMIC_RELAXED, __HIP_MEMORY_SCOPE_AGENT);
  // flags = -1  (h_{-1} ready)
  for (long e = tid; e < 128l; e += nth)
    __hip_atomic_store(&flg[e], -1, __ATOMIC_RELAXED, __HIP_MEMORY_SCOPE_AGENT);
}

// ---------------- persistent fused LSTM ----------------
// EXACT baseline structure (proven 2920us): 128 blocks = 2 batch-groups x 64
// hidden-slices, flags + UC h, whf in registers/AGPRs, interleaved h loads,
// 2 barriers. Two surgical deltas, both targeting the measured 334MB
// FETCH_SIZE (L3 pollution by the out write-back stream):
//  (1) out stores are NONTEMPORAL -> the 128MB output stream stops evicting
//      the 256KB h-exchange set + x from L3; h loads/polls become L3 hits.
//  (2) out stores issued AFTER the flag store -> the pre-flag __syncthreads
//      drains only the 2 UC h-publish stores, not the output write-backs
//      (they retire during the next step and drain for free at sync1).
__global__ void __launch_bounds__(256, 1)
lstm_kernel(const unsigned char* __restrict__ ws, float* __restrict__ out) {
  const unsigned short* xb   = (const unsigned short*)(ws + OFF_XB);
  const unsigned short* wxp  = (const unsigned short*)(ws + OFF_WXP);
  const unsigned short* whp  = (const unsigned short*)(ws + OFF_WHP);
  const float*          bias = (const float*)(ws + OFF_BIAS);
  unsigned short*       hbuf = (unsigned short*)(ws + OFF_HBUF);
  int*                  flg  = (int*)(ws + OFF_FLG);

  const int tid = threadIdx.x;
  const int wv = tid >> 6, lane = tid & 63;
  const int r = lane & 15, q = lane >> 4;          // MFMA frag row + k-quad
  const int s = blockIdx.x & 63, g = blockIdx.x >> 6;

  __shared__ float pc[4][8][64][4];                // [wave][tile][lane][reg], 32 KiB

  // ---- preload weights into registers (loop-invariant; AGPR-backed) ----
  bf16x8 whf[4][8];   // [nt][kk]
  bf16x8 wxf[4][2];   // [nt][kk]
#pragma unroll
  for (int nt = 0; nt < 4; ++nt) {
    const int c = nt * 1024 + s * 16 + r;
    const unsigned short* whb = whp + (long)c * 1024 + q * 8;
    const unsigned short* wxb = wxp + (long)c * 256 + q * 8;
#pragma unroll
    for (int kk = 0; kk < 8; ++kk) whf[nt][kk] = ld16(whb + wv * 256 + kk * 32);
#pragma unroll
    for (int kk = 0; kk < 2; ++kk) wxf[nt][kk] = ld16(wxb + wv * 64 + kk * 32);
  }

  const unsigned short* xa0 = xb + ((long)g * 32 + r) * 256 + q * 8;

  // epilogue mapping: thread -> (batches ebp, ebp+16 ; hidden j = ej)
  const int ej = tid & 15, ebp = tid >> 4;
  const int lidx = ej | ((ebp >> 2) << 4), rg = ebp & 3;   // C-frag coords
  float bs[4];
#pragma unroll
  for (int gt = 0; gt < 4; ++gt) bs[gt] = bias[gt * 1024 + s * 16 + ej];

  const unsigned long long* fl64 = (const unsigned long long*)flg;
  float cst[2] = {0.f, 0.f};

  for (int t = 0; t < 512; ++t) {
    floatx4 acc[2][4];
#pragma unroll
    for (int mt = 0; mt < 2; ++mt)
#pragma unroll
      for (int nt = 0; nt < 4; ++nt) acc[mt][nt] = (floatx4){0.f, 0.f, 0.f, 0.f};

    // ---- x-side K (no dependency; overlaps producers + hides poll) ----
    const unsigned short* xaT = xa0 + (long)t * (64 * 256);
#pragma unroll
    for (int kk = 0; kk < 2; ++kk) {
      const int k0 = wv * 64 + kk * 32;
      bf16x8 a0 = ld16(xaT + k0);
      bf16x8 a1 = ld16(xaT + 16 * 256 + k0);
#pragma unroll
      for (int nt = 0; nt < 4; ++nt) {
        acc[0][nt] = __builtin_amdgcn_mfma_f32_16x16x32_bf16(a0, wxf[nt][kk], acc[0][nt], 0, 0, 0);
        acc[1][nt] = __builtin_amdgcn_mfma_f32_16x16x32_bf16(a1, wxf[nt][kk], acc[1][nt], 0, 0, 0);
      }
    }

    // ---- wait: all 128 flags >= t-1 (each lane checks 2 flags; no barrier) ----
    {
      const int need = t - 1;
      while (true) {
        unsigned long long fv =
            __hip_atomic_load(&fl64[lane], __ATOMIC_RELAXED, __HIP_MEMORY_SCOPE_AGENT);
        bool ok = ((int)(unsigned int)fv >= need) && ((int)(unsigned int)(fv >> 32) >= need);
        if (__all(ok)) break;
        __builtin_amdgcn_s_sleep(1);
      }
    }
    asm volatile("" ::: "memory");

    // ---- h-side K (UC loads: L3-coherent, never stale, L2 untouched) ----
    const unsigned short* ha =
        hbuf + (long)((t - 1) & 1) * 65536 + ((long)g * 32 + r) * 1024 + q * 8;
#pragma unroll
    for (int kk = 0; kk < 8; ++kk) {
      const int k0 = wv * 256 + kk * 32;
      bf16x8 a0 = ldsys16(ha + k0);
      bf16x8 a1 = ldsys16(ha + 16 * 1024 + k0);
#pragma unroll
      for (int nt = 0; nt < 4; ++nt) {
        acc[0][nt] = __builtin_amdgcn_mfma_f32_16x16x32_bf16(a0, whf[nt][kk], acc[0][nt], 0, 0, 0);
        acc[1][nt] = __builtin_amdgcn_mfma_f32_16x16x32_bf16(a1, whf[nt][kk], acc[1][nt], 0, 0, 0);
      }
    }

    // ---- cross-wave K reduction via LDS ----
#pragma unroll
    for (int mt = 0; mt < 2; ++mt)
#pragma unroll
      for (int nt = 0; nt < 4; ++nt)
        *(floatx4*)(&pc[wv][mt * 4 + nt][lane][0]) = acc[mt][nt];
    __syncthreads();

    // ---- gates + state update ----
    float hv[2], cv[2];
#pragma unroll
    for (int e = 0; e < 2; ++e) {
      float gs[4];
#pragma unroll
      for (int gt = 0; gt < 4; ++gt) {
        float sv = bs[gt];
#pragma unroll
        for (int w2 = 0; w2 < 4; ++w2) sv += pc[w2][e * 4 + gt][lidx][rg];
        gs[gt] = sv;
      }
      const float f = fsig(gs[0]), ii = fsig(gs[1]), o = fsig(gs[2]);
      const float cd = ftanh(gs[3]);
      cst[e] = f * cst[e] + ii * cd;
      cv[e] = cst[e];
      hv[e] = o * ftanh(cst[e]);
    }

    // ---- publish h_t (bf16, UC write-through to L3) ----
    int emit = ((ej & 1) == 0);
#pragma unroll
    for (int e = 0; e < 2; ++e) {
      unsigned short hb = f2bf(hv[e]);
      unsigned short nb = (unsigned short)__shfl_xor((int)hb, 1, 64);
      if (emit) {
        unsigned int pv = (unsigned int)hb | ((unsigned int)nb << 16);
        unsigned int* hp = (unsigned int*)(hbuf + (long)(t & 1) * 65536 +
                                           (g * 32 + e * 16 + ebp) * 1024 + s * 16 + ej);
        __hip_atomic_store(hp, pv, __ATOMIC_RELAXED, __HIP_MEMORY_SCOPE_AGENT);
      }
    }
    __syncthreads();  // vmcnt(0): drains ONLY the 2 h publish stores (out
                      // stores now issued after the flag, delta #2)
    if (tid == 0)     // plain UC flag store — no RMW, no fence
      __hip_atomic_store(&flg[blockIdx.x], t, __ATOMIC_RELAXED, __HIP_MEMORY_SCOPE_AGENT);

    // ---- h_seq / finals: NONTEMPORAL stores (delta #1) issued after the
    // flag (delta #2); they retire during the next step and drain for free
    // at the next sync. nt keeps the 128MB stream from evicting the hot
    // h/x/weight lines out of L3 (FETCH_SIZE 334MB -> ideal ~30MB). ----
#pragma unroll
    for (int e = 0; e < 2; ++e) {
      const int bl = e * 16 + ebp;
      const long oidx = (long)t * 65536 + (g * 32 + bl) * 1024 + s * 16 + ej;
      __builtin_nontemporal_store(hv[e], &out[oidx]);
      if (t == 511) {
        __builtin_nontemporal_store(hv[e], &out[33554432l + (g * 32 + bl) * 1024 + s * 16 + ej]);
        __builtin_nontemporal_store(cv[e], &out[33619968l + (g * 32 + bl) * 1024 + s * 16 + ej]);
      }
    }
  }
}

extern "C" void kernel_launch(void* const* d_in, const int* in_sizes, int n_in,
                              void* d_out, int out_size, void* d_ws, size_t ws_size,
                              hipStream_t stream) {
  (void)in_sizes; (void)n_in; (void)out_size; (void)ws_size;
  KPtrs P;
  for (int i = 0; i < 17; ++i) P.p[i] = (const float*)d_in[i];
  pack_kernel<<<dim3(2048), dim3(256), 0, stream>>>(P, (unsigned char*)d_ws);
  lstm_kernel<<<dim3(128), dim3(256), 0, stream>>>((const unsigned char*)d_ws, (float*)d_out);
}